// Round 13
// baseline (88.468 us; speedup 1.0000x reference)
//
#include <hip/hip_runtime.h>
#include <hip/hip_bf16.h>

#define NEMIT 512
#define ZPLANES 8
#define ROISIZE 20
#define SPL_D 64
#define SPL_H 40
#define SPL_W 40
#define NPIX (ROISIZE * ROISIZE)   // 400
#define E 8                         // emitters per block (same as round-11)
#define NGROUPS (NEMIT / E)         // 64

// A/B vs round-11: SAME grid (8z x 64 groups, 512 thr), SAME E, but NO LDS
// slab / NO staging barriers. 8 lanes own one cell: lane sub holds float4 #sub
// and #(sub+8) of the cell's 64 coefs in registers (coalesced loads, proven in
// round 8), then loops E emitters with register-hoisted per-emitter basis
// (w0,w1,dx-powers; e-loop fully unrolled -> static reg indexing). 3x shfl_xor
// reduces each 8-lane group. Main loop is barrier-free; only the
// normalization needs 2 barriers at the end.
__global__ __launch_bounds__(512)
void psf_kernel(const float* __restrict__ pos,
                const float* __restrict__ inten,
                const float* __restrict__ bg,
                const float* __restrict__ coefs,
                float* __restrict__ out) {
    const int group = blockIdx.x >> 3;   // 64 groups
    const int z = blockIdx.x & 7;
    const int tid = threadIdx.x;
    const int gid = tid >> 3;            // 64 cell-groups
    const int sub = tid & 7;

    __shared__ float4 sdxv[E];           // (dx, dx2, dx3, I)
    __shared__ float2 spw[E][8];         // per-sub (w0, w1)
    __shared__ int4   spint[E];          // (iz, cy, cx, match)
    __shared__ float  sB[E];
    __shared__ float  sscale[E];
    __shared__ float  vals[E * NPIX];    // 12.8 KB

    // ---- phase 0: per-emitter params (threads 0..63: e = tid>>3, s = tid&7) ----
    if (tid < E * 8) {
        const int e = tid >> 3;
        const int s = tid & 7;
        const int n = group * E + e;
        const float p0 = pos[n * 3 + 0];
        const float p1 = pos[n * 3 + 1];
        const float p2 = pos[n * 3 + 2];
        const float azf = (float)z - p2 + 28.0f;
        const float fzf = floorf(azf);
        const float dz = azf - fzf;
        int iz = (int)fzf; iz = min(max(iz, 0), SPL_D - 1);
        const float ayf = 10.0f - p0;
        const float fyf = floorf(ayf);
        const float dy = ayf - fyf;
        const int cy = (int)fyf;
        const float axf = 10.0f - p1;
        const float fxf = floorf(axf);
        const float dx = axf - fxf;
        const int cx = (int)fxf;
        const float pz[4] = {1.0f, dz, dz * dz, dz * dz * dz};
        const float py[4] = {1.0f, dy, dy * dy, dy * dy * dy};
        const float pyw = py[s & 3];
        spw[e][s] = make_float2(pz[s >> 2] * pyw, pz[2 + (s >> 2)] * pyw);
        if (s == 0) {
            sdxv[e] = make_float4(dx, dx * dx, dx * dx * dx, inten[n * ZPLANES + z]);
            sB[e] = bg[n * ZPLANES + z];
            const int match = (iz == z + 27) && (cy == 9) && (cx == 9);
            spint[e] = make_int4(iz, cy, cx, match);
        }
    }
    __syncthreads();

    // ---- hoist per-emitter params into registers (unrolled -> static idx) ----
    float4 dxv[E];
    float w0r[E], w1r[E];
    int matchr[E];
#pragma unroll
    for (int e = 0; e < E; ++e) {
        dxv[e] = sdxv[e];
        const float2 w = spw[e][sub];
        w0r[e] = w.x; w1r[e] = w.y;
        matchr[e] = spint[e].w;
    }

    const float* slabBase = coefs + (((size_t)(z + 27) * SPL_H + 9) * SPL_W + 9) * 64;

    // ---- main loop: 7 passes x 64 cells, barrier-free ----
#pragma unroll 1
    for (int p = 0; p < 7; ++p) {
        const int c = p * 64 + gid;          // cell index
        const bool valid = c < NPIX;
        const int y = c / ROISIZE;
        const int x = c - y * ROISIZE;
        // generic-path coefs (in-bounds even for the few invalid tail cells)
        const float4* cp = (const float4*)(slabBase + ((size_t)y * SPL_W + x) * 64);
        const float4 A0 = cp[sub];
        const float4 A1 = cp[sub + 8];
#pragma unroll
        for (int e = 0; e < E; ++e) {
            float4 a0 = A0, a1 = A1;
            if (!matchr[e]) {
                // cold fallback: emitter-specific cell gather (block-uniform branch)
                const int4 pe = spint[e];
                int iy = y + pe.y; iy = min(max(iy, 0), SPL_H - 1);
                int ix = x + pe.z; ix = min(max(ix, 0), SPL_W - 1);
                const float4* cpe = (const float4*)(coefs + (((size_t)pe.x * SPL_H + iy) * SPL_W + ix) * 64);
                a0 = cpe[sub];
                a1 = cpe[sub + 8];
            }
            const float4 d = dxv[e];
            const float sx0 = fmaf(a0.w, d.z, fmaf(a0.z, d.y, fmaf(a0.y, d.x, a0.x)));
            const float sx1 = fmaf(a1.w, d.z, fmaf(a1.z, d.y, fmaf(a1.y, d.x, a1.x)));
            float v = fmaf(w1r[e], sx1, w0r[e] * sx0);
            v += __shfl_xor(v, 1);
            v += __shfl_xor(v, 2);
            v += __shfl_xor(v, 4);
            if (valid && sub == 0) vals[e * NPIX + c] = v;
        }
    }
    __syncthreads();

    // ---- per-emitter totals: wave w reduces emitter w (E == 8 waves) ----
    const int wid = tid >> 6;
    const int lane = tid & 63;
    {
        float s = 0.0f;
        for (int c = lane; c < NPIX; c += 64) s += vals[wid * NPIX + c];
#pragma unroll
        for (int off = 32; off > 0; off >>= 1) s += __shfl_down(s, off);
        if (lane == 0) sscale[wid] = sdxv[wid].w / s;   // I / total
    }
    __syncthreads();

    // ---- scale + background + store (coalesced, threads 0..399) ----
    if (tid < NPIX) {
#pragma unroll
        for (int e = 0; e < E; ++e) {
            const size_t n = (size_t)(group * E + e);
            out[(n * ZPLANES + z) * NPIX + tid] = fmaf(vals[e * NPIX + tid], sscale[e], sB[e]);
        }
    }
}

extern "C" void kernel_launch(void* const* d_in, const int* in_sizes, int n_in,
                              void* d_out, int out_size, void* d_ws, size_t ws_size,
                              hipStream_t stream) {
    const float* pos   = (const float*)d_in[0];   // [512, 3]
    const float* inten = (const float*)d_in[1];   // [512, 8]
    const float* bg    = (const float*)d_in[2];   // [512, 8]
    const float* coefs = (const float*)d_in[3];   // [64, 40, 40, 64]
    float* out = (float*)d_out;                   // [512, 8, 20, 20]

    psf_kernel<<<ZPLANES * NGROUPS, 512, 0, stream>>>(pos, inten, bg, coefs, out);
}